// Round 17
// baseline (67.230 us; speedup 1.0000x reference)
//
#include <hip/hip_runtime.h>

typedef short bf16x8 __attribute__((ext_vector_type(8)));
typedef float f32x16 __attribute__((ext_vector_type(16)));

#define CIN 64
#define OC 18
#define NB 4
#define H 256
#define W 256
#define HW (H * W)
#define OH 128
#define OW 128
#define EPS 1e-5f

#define TSX 16          // tile cols
#define TSY 8           // tile rows (1 strip of 2 rows per wave, 4 waves)
#define NTILE 4         // tiles per block (along W)
#define WPX 36          // LDS words per pixel (32 data + 4 pad)
#define ROWW (18 * WPX) // 648 words per halo row
#define AWORDS (10 * ROWW)  // 6480 words = 25.9 KB per buffer
#define NWB 512         // number of conv blocks

// ws layout (floats):
//   [0..255]   (header, unused)
//   [256 ...]  sigma_s [NB][OC][OH][OW]  (1,179,648 floats, planar)
//   then       wB  (36*64 uint4)
//   then       x_t NHWC bf16 [NB][H][W][CIN]  (2,097,152 uint4)
//   then       part [36][NWB] floats (per-block BN partials)

__device__ __forceinline__ int refl(int i, int n) {
    if (i < 0) i = -i;
    if (i >= n) i = 2 * n - 2 - i;
    return i;
}

__device__ __forceinline__ unsigned pack_bf16(float a, float b) {
    __bf16 lo = (__bf16)a, hi = (__bf16)b;
    return (unsigned)__builtin_bit_cast(unsigned short, lo) |
           ((unsigned)__builtin_bit_cast(unsigned short, hi) << 16);
}

// ---------------------------------------------------------------------------
// NCHW fp32 -> NHWC bf16 transpose (+ fused weight repack on blockIdx.y==NB).
// ---------------------------------------------------------------------------
__global__ __launch_bounds__(256) void nhwc_kernel(
        const float* __restrict__ x, uint4* __restrict__ xt,
        const float* __restrict__ wgt, uint4* __restrict__ wB)
{
    if (blockIdx.y == NB) {
        if (blockIdx.x < 9) {
            int idx = blockIdx.x * 256 + threadIdx.x;   // s*64 + l
            int s = idx >> 6, l = idx & 63;
            int tap = s >> 2, ci0 = (s & 3) * 16;
            int oc = l & 31, kg = l >> 5;
            unsigned r[4];
#pragma unroll
            for (int jp = 0; jp < 4; jp++) {
                float v0 = 0.f, v1 = 0.f;
                int ci = ci0 + kg * 8 + jp * 2;
                if (oc < OC) {
                    v0 = wgt[(oc * CIN + ci) * 9 + tap];
                    v1 = wgt[(oc * CIN + ci + 1) * 9 + tap];
                }
                r[jp] = pack_bf16(v0, v1);
            }
            wB[idx] = make_uint4(r[0], r[1], r[2], r[3]);
        }
        return;
    }

    __shared__ uint4 bufq[2048];          // 32 KB
    unsigned* buf = (unsigned*)bufq;

    const int h = blockIdx.x, n = blockIdx.y;
    const int t = threadIdx.x;
    const int tpx = t & 63;
    const int cg = t >> 6;
    const int px0 = tpx * 4;
    const unsigned swz = ((unsigned)tpx & 7u) << 2;

    const float* xrow = x + ((size_t)n * CIN * H + h) * W;

#pragma unroll
    for (int ii = 0; ii < 4; ii++) {
        const int cq = cg * 4 + ii;
        const float4 A0 = *(const float4*)(xrow + (size_t)(4 * cq + 0) * HW + px0);
        const float4 A1 = *(const float4*)(xrow + (size_t)(4 * cq + 1) * HW + px0);
        const float4 A2 = *(const float4*)(xrow + (size_t)(4 * cq + 2) * HW + px0);
        const float4 A3 = *(const float4*)(xrow + (size_t)(4 * cq + 3) * HW + px0);
        const float a0[4] = {A0.x, A0.y, A0.z, A0.w};
        const float a1[4] = {A1.x, A1.y, A1.z, A1.w};
        const float a2[4] = {A2.x, A2.y, A2.z, A2.w};
        const float a3[4] = {A3.x, A3.y, A3.z, A3.w};
#pragma unroll
        for (int i = 0; i < 4; i++) {
            unsigned lo = pack_bf16(a0[i], a1[i]);
            unsigned hi = pack_bf16(a2[i], a3[i]);
            unsigned widx = (unsigned)(px0 + i) * 32u + ((unsigned)(2 * cq) ^ swz);
            *(uint2*)&buf[widx] = make_uint2(lo, hi);
        }
    }
    __syncthreads();

    const size_t rowbase = ((size_t)(n * H + h)) * W * 8;
#pragma unroll
    for (int i = 0; i < 8; i++) {
        int flat = i * 256 + t;
        int px = flat >> 3, j = flat & 7;
        unsigned sw = (((unsigned)px >> 2) & 7u) << 2;
        uint4 v = *(const uint4*)&buf[(unsigned)px * 32u + (((unsigned)(4 * j)) ^ sw)];
        xt[rowbase + flat] = v;
    }
}

// ---------------------------------------------------------------------------
// Kernel A: persistent-tile implicit-GEMM bf16 MFMA conv (r16, unchanged).
// Block = 8 rows x 64 cols = 4 tiles of 16x8. A in LDS (2-buffer rotation,
// ONE barrier per tile); B compact in LDS (36 steps x 37 slots, slot 36 = 0).
// Per-block BN partials to part[36][NWB] (no global atomics).
// D (32x32): col = lane&31 = oc, row = (reg&3)+8*(reg>>2)+4*(lane>>5) = pixel.
// ---------------------------------------------------------------------------
__global__ __launch_bounds__(256, 2) void conv_kernel(
        const uint4* __restrict__ xt, const uint4* __restrict__ wB,
        float* __restrict__ sigma_s, float* __restrict__ part)
{
    __shared__ unsigned alds[2][AWORDS];   // 51.8 KB
    __shared__ uint4 wlds[36 * 37];        // 21.3 KB
    __shared__ float sred[2 * OC];

    const int tid = threadIdx.x;
    const int lane = tid & 63;

    const int b = blockIdx.x;
    const int cls = b & 7;
    const int L = b >> 3;                  // 0..63
    const int n = cls >> 1;
    const int hhalf = cls & 1;
    const int ht = L >> 2;                 // 0..15
    const int wq = L & 3;                  // 0..3
    const int h0 = (hhalf * 16 + ht) * TSY;
    const int w0 = wq * (NTILE * TSX);

    if (tid < 2 * OC) sred[tid] = 0.f;

    int  gbase[6], alw[6], apx[6];
    bool av[6];
#pragma unroll
    for (int i = 0; i < 6; i++) {
        int e = tid + i * 256;
        av[i] = e < 1440;
        if (!av[i]) e = 1439;
        int row = e / 144;
        int rr  = e - row * 144;
        int px  = rr >> 3;
        int c   = rr & 7;
        int gh  = refl(h0 + row - 1, H);
        gbase[i] = (n * H + gh) * W * 8 + c;
        apx[i]  = px;
        alw[i]  = row * ROWW + px * WPX + c * 4;
    }

    {
        uint4 wst[6];
        bool  wv6[6];
        int   we[6];
#pragma unroll
        for (int i = 0; i < 6; i++) {
            int e = tid + i * 256;
            wv6[i] = e < 36 * 37;
            we[i] = e;
            if (wv6[i]) {
                int s = e / 37, j = e - s * 37;
                uint4 v = make_uint4(0, 0, 0, 0);
                if (j < 36) {
                    int kgj = j / OC, ocj = j - kgj * OC;
                    v = wB[s * 64 + kgj * 32 + ocj];
                }
                wst[i] = v;
            }
        }
        uint4 ast[6];
#pragma unroll
        for (int i = 0; i < 6; i++) {
            if (av[i]) {
                int gw = refl(w0 + apx[i] - 1, W);
                ast[i] = xt[(size_t)gbase[i] + (size_t)gw * 8];
            }
        }
#pragma unroll
        for (int i = 0; i < 6; i++)
            if (wv6[i]) wlds[we[i]] = wst[i];
#pragma unroll
        for (int i = 0; i < 6; i++)
            if (av[i]) *(uint4*)&alds[0][alw[i]] = ast[i];
    }
    __syncthreads();

    const int wv = tid >> 6;
    const int m = lane & 31;
    const int kg = lane >> 5;
    const int pr = m >> 4, pc = m & 15;
    const int r0 = 2 * wv + pr;
    const int abase = r0 * ROWW + pc * WPX + kg * 4;
    const int bidx = (m < OC) ? (kg * OC + m) : 36;

    float s_acc = 0.f, ss_acc = 0.f;
    const int oy = (h0 >> 1) + wv;
    const size_t pb_n = (size_t)n * OC;

#pragma unroll 1
    for (int t = 0; t < NTILE; t++) {
        uint4 pfa[6];
        if (t + 1 < NTILE) {
            const int w0n = w0 + (t + 1) * TSX;
#pragma unroll
            for (int i = 0; i < 6; i++) {
                if (av[i]) {
                    int gw = refl(w0n + apx[i] - 1, W);
                    pfa[i] = xt[(size_t)gbase[i] + (size_t)gw * 8];
                }
            }
        }

        const unsigned* ap = &alds[t & 1][abase];
        f32x16 acc = {};
#pragma unroll
        for (int g = 0; g < 9; g++) {
            const int kh = g / 3, kw = g % 3;
#pragma unroll
            for (int q = 0; q < 4; q++) {
                uint4 af = *(const uint4*)(ap + kh * ROWW + kw * WPX + q * 8);
                uint4 bf = wlds[(g * 4 + q) * 37 + bidx];
                acc = __builtin_amdgcn_mfma_f32_32x32x16_bf16(
                        __builtin_bit_cast(bf16x8, af),
                        __builtin_bit_cast(bf16x8, bf), acc, 0, 0, 0);
            }
        }

#pragma unroll
        for (int rr = 0; rr < 16; rr++) {
            s_acc  += acc[rr];
            ss_acc += acc[rr] * acc[rr];
        }
        if (m < OC) {
            const int ox0 = (w0 + t * TSX) >> 1;
            const size_t pbase = ((pb_n + m) * OH + oy) * OW;
#pragma unroll
            for (int rr = 0; rr < 16; rr++) {
                int p = (rr & 3) + 8 * (rr >> 2) + 4 * kg;
                if (p < 16 && (p & 1) == 0)
                    sigma_s[pbase + ox0 + (p >> 1)] = acc[rr];
            }
        }

        if (t + 1 < NTILE) {
#pragma unroll
            for (int i = 0; i < 6; i++)
                if (av[i]) *(uint4*)&alds[(t + 1) & 1][alw[i]] = pfa[i];
        }
        __syncthreads();
    }

    s_acc  += __shfl_xor(s_acc, 32);
    ss_acc += __shfl_xor(ss_acc, 32);
    if (kg == 0 && m < OC) {
        atomicAdd(&sred[m], s_acc);
        atomicAdd(&sred[OC + m], ss_acc);
    }
    __syncthreads();
    if (tid < 2 * OC) part[tid * NWB + blockIdx.x] = sred[tid];
}

// ---------------------------------------------------------------------------
// Kernel C: BN finalize (redundant per block, from part) + affine +
// softmax(18) + 9-tap aggregation from NHWC bf16.
// 1-D grid, XCD-matched: bid%8 = cls = (n<<1)|(oh>=64) — same class decode
// as the conv block that produced this sigma region (L2 locality).
// ---------------------------------------------------------------------------
__global__ __launch_bounds__(256) void out_kernel(
        const uint4* __restrict__ xt, const float* __restrict__ sigma_s,
        const float* __restrict__ part,
        const float* __restrict__ gamma, const float* __restrict__ beta,
        float* __restrict__ out)
{
    __shared__ float p_lds[OC][64];
    __shared__ float sred2[36 * 4];
    __shared__ float sscale[OC], sshift[OC];

    const int tid = threadIdx.x;

    // decode: bid = idx*8 + cls ; cls = (n<<1)|hhalf ; idx = (oh&63)*2 + owhalf
    const int bid = blockIdx.x;
    const int cls = bid & 7;
    const int idx = bid >> 3;              // 0..127
    const int n = cls >> 1;
    const int oh = (cls & 1) * 64 + (idx >> 1);
    const int ow0 = (idx & 1) * 64;
    const int h = 2 * oh;

    // ---- BN finalize from part[36][NWB] (73 KB, L2-resident) ----
    if (tid < 144) {
        int row = tid >> 2, q = tid & 3;
        const float4* p4 = (const float4*)(part + row * NWB) + q * 32;
        float s = 0.f;
#pragma unroll 8
        for (int k = 0; k < 32; k++) {
            float4 v = p4[k];
            s += (v.x + v.y) + (v.z + v.w);
        }
        sred2[row * 4 + q] = s;
    }
    __syncthreads();
    if (tid < OC) {
        float S = sred2[tid * 4] + sred2[tid * 4 + 1] + sred2[tid * 4 + 2] + sred2[tid * 4 + 3];
        float Q = sred2[(OC + tid) * 4] + sred2[(OC + tid) * 4 + 1] +
                  sred2[(OC + tid) * 4 + 2] + sred2[(OC + tid) * 4 + 3];
        float cf = (float)NB * H * W;
        float mean = S / cf;
        float var  = Q / cf - mean * mean;
        float sc   = gamma[tid] * rsqrtf(var + EPS);
        sscale[tid] = sc;
        sshift[tid] = beta[tid] - mean * sc;
    }
    __syncthreads();

    // ---- sigma load (planar) + affine ----
    for (int i = tid; i < OC * 64; i += 256) {
        int ch = i >> 6, owl = i & 63;
        float v = sigma_s[((size_t)(n * OC + ch) * OH + oh) * OW + ow0 + owl];
        p_lds[ch][owl] = v * sscale[ch] + sshift[ch];
    }
    __syncthreads();

    // ---- softmax per pixel ----
    if (tid < 64) {
        int owl = tid;
        float mx = -1e30f;
#pragma unroll
        for (int ch = 0; ch < OC; ch++) mx = fmaxf(mx, p_lds[ch][owl]);
        float e[OC], sum = 0.f;
#pragma unroll
        for (int ch = 0; ch < OC; ch++) { e[ch] = __expf(p_lds[ch][owl] - mx); sum += e[ch]; }
        float inv = 1.f / sum;
#pragma unroll
        for (int ch = 0; ch < OC; ch++) p_lds[ch][owl] = e[ch] * inv;
    }
    __syncthreads();

    int ihs[3];
#pragma unroll
    for (int kh = 0; kh < 3; kh++) ihs[kh] = refl(h - 1 + kh, H);

#pragma unroll
    for (int it = 0; it < 2; it++) {
        const int flat = it * 256 + tid;
        const int c8 = flat & 7;
        const int owl = flat >> 3;
        const int ow = ow0 + owl;
        const int g = (c8 >= 4) ? 1 : 0;

        float a[8];
#pragma unroll
        for (int j = 0; j < 8; j++) a[j] = 0.f;

#pragma unroll
        for (int kh = 0; kh < 3; kh++) {
            const size_t rb = ((size_t)(n * H + ihs[kh])) * W * 8;
#pragma unroll
            for (int kw = 0; kw < 3; kw++) {
                const int iw = refl(2 * ow - 1 + kw, W);
                const float p = p_lds[g * 9 + kh * 3 + kw][owl];
                uint4 v = xt[rb + (size_t)iw * 8 + c8];
                const unsigned uu[4] = {v.x, v.y, v.z, v.w};
#pragma unroll
                for (int q = 0; q < 4; q++) {
                    float lo = __builtin_bit_cast(float, uu[q] << 16);
                    float hi = __builtin_bit_cast(float, uu[q] & 0xffff0000u);
                    a[2 * q]     = fmaf(p, lo, a[2 * q]);
                    a[2 * q + 1] = fmaf(p, hi, a[2 * q + 1]);
                }
            }
        }

        const size_t ob = ((size_t)(n * CIN + c8 * 8) * OH + oh) * OW + ow;
#pragma unroll
        for (int j = 0; j < 8; j++)
            out[ob + (size_t)j * OH * OW] = a[j];
    }
}

// ---------------------------------------------------------------------------
extern "C" void kernel_launch(void* const* d_in, const int* in_sizes, int n_in,
                              void* d_out, int out_size, void* d_ws, size_t ws_size,
                              hipStream_t stream) {
    const float* x     = (const float*)d_in[0];
    const float* cw    = (const float*)d_in[1];
    const float* gamma = (const float*)d_in[2];
    const float* beta  = (const float*)d_in[3];
    float* out = (float*)d_out;
    float* ws  = (float*)d_ws;

    float* sigma_s = ws + 256;                              // 1,179,648 floats
    uint4* wBp     = (uint4*)(sigma_s + (size_t)NB * OC * OH * OW);   // 2304 uint4
    uint4* xtp     = wBp + 36 * 64;                         // 2,097,152 uint4
    float* part    = (float*)(xtp + (size_t)NB * H * W * 8);          // 36*512 floats

    dim3 gT(H, NB + 1);   // y==NB does the weight repack
    nhwc_kernel<<<gT, 256, 0, stream>>>(x, xtp, cw, wBp);

    conv_kernel<<<dim3(NWB), 256, 0, stream>>>(xtp, wBp, sigma_s, part);

    out_kernel<<<dim3(NB * 2 * OH), 256, 0, stream>>>(xtp, sigma_s, part,
                                                      gamma, beta, out);
}

// Round 18
// 51.601 us; speedup vs baseline: 1.3029x; 1.3029x over previous
//
#include <hip/hip_runtime.h>

typedef short bf16x8 __attribute__((ext_vector_type(8)));
typedef float f32x16 __attribute__((ext_vector_type(16)));

#define CIN 64
#define OC 18
#define NB 4
#define H 256
#define W 256
#define HW (H * W)
#define OH 128
#define OW 128
#define EPS 1e-5f

#define TSX 16          // tile cols
#define TSY 8           // tile rows (1 strip of 2 rows per wave, 4 waves)
#define NTILE 4         // tiles per block (along W)
#define NWB 512         // number of conv blocks
// A halo: 10 rows x 18 px x 8 uint4 = 1440 uint4, padded to 1536 (gload overrun)
#define ASLOTS 1536

// ws layout (floats):
//   [0..255]   stats (36..53 scale, 54..71 shift)
//   [256 ...]  sigma_s [NB][OC][OH][OW]  (1,179,648 floats, planar)
//   then       wB  (36*64 uint4)
//   then       x_t NHWC bf16 [NB][H][W][CIN]  (2,097,152 uint4)
//   then       part [36][NWB] floats (per-block BN partials)

__device__ __forceinline__ int refl(int i, int n) {
    if (i < 0) i = -i;
    if (i >= n) i = 2 * n - 2 - i;
    return i;
}

__device__ __forceinline__ unsigned pack_bf16(float a, float b) {
    __bf16 lo = (__bf16)a, hi = (__bf16)b;
    return (unsigned)__builtin_bit_cast(unsigned short, lo) |
           ((unsigned)__builtin_bit_cast(unsigned short, hi) << 16);
}

__device__ __forceinline__ void gload_lds16(const uint4* g, uint4* l) {
    __builtin_amdgcn_global_load_lds(
        (const __attribute__((address_space(1))) void*)(g),
        (__attribute__((address_space(3))) void*)(l), 16, 0, 0);
}

// ---------------------------------------------------------------------------
// NCHW fp32 -> NHWC bf16 transpose (+ fused weight repack on blockIdx.y==NB).
// ---------------------------------------------------------------------------
__global__ __launch_bounds__(256) void nhwc_kernel(
        const float* __restrict__ x, uint4* __restrict__ xt,
        const float* __restrict__ wgt, uint4* __restrict__ wB)
{
    if (blockIdx.y == NB) {
        if (blockIdx.x < 9) {
            int idx = blockIdx.x * 256 + threadIdx.x;   // s*64 + l
            int s = idx >> 6, l = idx & 63;
            int tap = s >> 2, ci0 = (s & 3) * 16;
            int oc = l & 31, kg = l >> 5;
            unsigned r[4];
#pragma unroll
            for (int jp = 0; jp < 4; jp++) {
                float v0 = 0.f, v1 = 0.f;
                int ci = ci0 + kg * 8 + jp * 2;
                if (oc < OC) {
                    v0 = wgt[(oc * CIN + ci) * 9 + tap];
                    v1 = wgt[(oc * CIN + ci + 1) * 9 + tap];
                }
                r[jp] = pack_bf16(v0, v1);
            }
            wB[idx] = make_uint4(r[0], r[1], r[2], r[3]);
        }
        return;
    }

    __shared__ uint4 bufq[2048];          // 32 KB
    unsigned* buf = (unsigned*)bufq;

    const int h = blockIdx.x, n = blockIdx.y;
    const int t = threadIdx.x;
    const int tpx = t & 63;
    const int cg = t >> 6;
    const int px0 = tpx * 4;
    const unsigned swz = ((unsigned)tpx & 7u) << 2;

    const float* xrow = x + ((size_t)n * CIN * H + h) * W;

#pragma unroll
    for (int ii = 0; ii < 4; ii++) {
        const int cq = cg * 4 + ii;
        const float4 A0 = *(const float4*)(xrow + (size_t)(4 * cq + 0) * HW + px0);
        const float4 A1 = *(const float4*)(xrow + (size_t)(4 * cq + 1) * HW + px0);
        const float4 A2 = *(const float4*)(xrow + (size_t)(4 * cq + 2) * HW + px0);
        const float4 A3 = *(const float4*)(xrow + (size_t)(4 * cq + 3) * HW + px0);
        const float a0[4] = {A0.x, A0.y, A0.z, A0.w};
        const float a1[4] = {A1.x, A1.y, A1.z, A1.w};
        const float a2[4] = {A2.x, A2.y, A2.z, A2.w};
        const float a3[4] = {A3.x, A3.y, A3.z, A3.w};
#pragma unroll
        for (int i = 0; i < 4; i++) {
            unsigned lo = pack_bf16(a0[i], a1[i]);
            unsigned hi = pack_bf16(a2[i], a3[i]);
            unsigned widx = (unsigned)(px0 + i) * 32u + ((unsigned)(2 * cq) ^ swz);
            *(uint2*)&buf[widx] = make_uint2(lo, hi);
        }
    }
    __syncthreads();

    const size_t rowbase = ((size_t)(n * H + h)) * W * 8;
#pragma unroll
    for (int i = 0; i < 8; i++) {
        int flat = i * 256 + t;
        int px = flat >> 3, j = flat & 7;
        unsigned sw = (((unsigned)px >> 2) & 7u) << 2;
        uint4 v = *(const uint4*)&buf[(unsigned)px * 32u + (((unsigned)(4 * j)) ^ sw)];
        xt[rowbase + flat] = v;
    }
}

// ---------------------------------------------------------------------------
// Kernel A: persistent-tile implicit-GEMM bf16 MFMA conv.
// Block = 8 rows x 64 cols = 4 tiles of 16x8. A staged via ASYNC
// global_load_lds width-16 (linear LDS, source channel-octet pre-swizzled
// c^=(px&7); reads XOR the same involution -> <=2-way conflicts).
// B compact in LDS (36 steps x 37 slots, slot 36 = 0). ONE barrier per tile.
// Per-block BN partials to part[36][NWB] (no global atomics).
// D (32x32): col = lane&31 = oc, row = (reg&3)+8*(reg>>2)+4*(lane>>5) = pixel.
// ---------------------------------------------------------------------------
__global__ __launch_bounds__(256, 2) void conv_kernel(
        const uint4* __restrict__ xt, const uint4* __restrict__ wB,
        float* __restrict__ sigma_s, float* __restrict__ part)
{
    __shared__ uint4 aldsq[2][ASLOTS];     // 2 x 24,576 B
    __shared__ uint4 wlds[36 * 37];        // 21,312 B (compact B)
    __shared__ float sred[2 * OC];

    const int tid = threadIdx.x;
    const int lane = tid & 63;

    // decode: cls = (n, hhalf); L -> (ht_local, wquad)
    const int b = blockIdx.x;
    const int cls = b & 7;
    const int L = b >> 3;                  // 0..63
    const int n = cls >> 1;
    const int hhalf = cls & 1;
    const int ht = L >> 2;                 // 0..15
    const int wq = L & 3;                  // 0..3
    const int h0 = (hhalf * 16 + ht) * TSY;
    const int w0 = wq * (NTILE * TSX);

    if (tid < 2 * OC) sred[tid] = 0.f;

    // ---- t-invariant A staging map (6 elements/thread; no clamp) ----
    // e = tid + i*256 -> (row, px, cs); content = octet cs ^ (px&7)
    int gbase[6], apx[6];
#pragma unroll
    for (int i = 0; i < 6; i++) {
        int e = tid + i * 256;             // < 1536
        int row = e / 144;
        int rem = e - row * 144;
        int px  = rem >> 3;
        int cs  = rem & 7;
        int csrc = cs ^ (px & 7);
        int gh  = refl(h0 + row - 1, H);
        gbase[i] = (n * H + gh) * W * 8 + csrc;
        apx[i]  = px;
    }

    // ---- stage B (plain loads) + issue A tile 0 (async) ----
    {
        uint4 wst[6];
        bool  wv6[6];
#pragma unroll
        for (int i = 0; i < 6; i++) {
            int e = tid + i * 256;
            wv6[i] = e < 36 * 37;
            if (wv6[i]) {
                int s = e / 37, j = e - s * 37;
                uint4 v = make_uint4(0, 0, 0, 0);
                if (j < 36) {
                    int kgj = j / OC, ocj = j - kgj * OC;
                    v = wB[s * 64 + kgj * 32 + ocj];
                }
                wst[i] = v;
            }
        }
#pragma unroll
        for (int i = 0; i < 6; i++) {
            int gw = refl(w0 + apx[i] - 1, W);
            gload_lds16(xt + (size_t)gbase[i] + (size_t)gw * 8,
                        &aldsq[0][tid + i * 256]);
        }
#pragma unroll
        for (int i = 0; i < 6; i++)
            if (wv6[i]) wlds[tid + i * 256] = wst[i];
    }
    __syncthreads();   // drains vmcnt + lgkmcnt

    // ---- lane geometry ----
    const int wv = tid >> 6;
    const int m = lane & 31;
    const int kg = lane >> 5;
    const int pr = m >> 4, pc = m & 15;
    const int r0 = 2 * wv + pr;
    const int bidx = (m < OC) ? (kg * OC + m) : 36;   // compact B (36 = zero slot)

    float s_acc = 0.f, ss_acc = 0.f;
    const int oy = (h0 >> 1) + wv;
    const size_t pb_n = (size_t)n * OC;

#pragma unroll 1
    for (int t = 0; t < NTILE; t++) {
        // issue next tile's A loads ASYNC into the other buffer
        // (its readers were tile t-1, done at the barrier that ended t-1)
        if (t + 1 < NTILE) {
            const int w0n = w0 + (t + 1) * TSX;
            uint4* dst = &aldsq[(t + 1) & 1][0];
#pragma unroll
            for (int i = 0; i < 6; i++) {
                int gw = refl(w0n + apx[i] - 1, W);
                gload_lds16(xt + (size_t)gbase[i] + (size_t)gw * 8,
                            dst + tid + i * 256);
            }
        }

        // compute tile t from aldsq[t&1] (swizzled read), B from compact LDS
        const uint4* aq = &aldsq[t & 1][0];
        f32x16 acc = {};
#pragma unroll
        for (int g = 0; g < 9; g++) {
            const int kh = g / 3, kw = g % 3;
            const int rp  = (r0 + kh) * 144 + (pc + kw) * 8;
            const int swk = (pc + kw) & 7;
#pragma unroll
            for (int q = 0; q < 4; q++) {
                uint4 af = aq[rp + ((kg + 2 * q) ^ swk)];
                uint4 bf = wlds[(g * 4 + q) * 37 + bidx];
                acc = __builtin_amdgcn_mfma_f32_32x32x16_bf16(
                        __builtin_bit_cast(bf16x8, af),
                        __builtin_bit_cast(bf16x8, bf), acc, 0, 0, 0);
            }
        }

        // stats accumulate + strided sigma store (planar)
#pragma unroll
        for (int rr = 0; rr < 16; rr++) {
            s_acc  += acc[rr];
            ss_acc += acc[rr] * acc[rr];
        }
        if (m < OC) {
            const int ox0 = (w0 + t * TSX) >> 1;
            const size_t pbase = ((pb_n + m) * OH + oy) * OW;
#pragma unroll
            for (int rr = 0; rr < 16; rr++) {
                int p = (rr & 3) + 8 * (rr >> 2) + 4 * kg;
                if (p < 16 && (p & 1) == 0)
                    sigma_s[pbase + ox0 + (p >> 1)] = acc[rr];
            }
        }

        __syncthreads();   // next buffer's async loads drained here
    }

    // ---- BN partials: block-local reduce, one plain store per channel ----
    s_acc  += __shfl_xor(s_acc, 32);
    ss_acc += __shfl_xor(ss_acc, 32);
    if (kg == 0 && m < OC) {
        atomicAdd(&sred[m], s_acc);
        atomicAdd(&sred[OC + m], ss_acc);
    }
    __syncthreads();
    if (tid < 2 * OC) part[tid * NWB + blockIdx.x] = sred[tid];
}

// ---------------------------------------------------------------------------
// Kernel B: reduce per-block partials + finalize BN -> scale/shift.
// ---------------------------------------------------------------------------
__global__ __launch_bounds__(256) void bn_kernel(
        const float* __restrict__ gamma, const float* __restrict__ beta,
        const float* __restrict__ part, float* __restrict__ stats)
{
    __shared__ float red[8];
    const int c = blockIdx.x;
    const int tid = threadIdx.x;

    float s  = part[c * NWB + tid]        + part[c * NWB + 256 + tid];
    float ss = part[(OC + c) * NWB + tid] + part[(OC + c) * NWB + 256 + tid];
#pragma unroll
    for (int off = 32; off > 0; off >>= 1) {
        s  += __shfl_down(s, off);
        ss += __shfl_down(ss, off);
    }
    const int wid = tid >> 6, lanez = tid & 63;
    if (lanez == 0) { red[wid] = s; red[4 + wid] = ss; }
    __syncthreads();
    if (tid == 0) {
        float S  = red[0] + red[1] + red[2] + red[3];
        float SS = red[4] + red[5] + red[6] + red[7];
        float cnt = (float)NB * H * W;
        float mean = S / cnt;
        float var  = SS / cnt - mean * mean;
        float sc   = gamma[c] * rsqrtf(var + EPS);
        stats[36 + c] = sc;
        stats[54 + c] = beta[c] - mean * sc;
    }
}

// ---------------------------------------------------------------------------
// Kernel C: BN-affine + softmax(18) + 9-tap aggregation from NHWC bf16.
// ---------------------------------------------------------------------------
__global__ __launch_bounds__(256) void out_kernel(
        const uint4* __restrict__ xt, const float* __restrict__ sigma_s,
        const float* __restrict__ stats, float* __restrict__ out)
{
    __shared__ float p_lds[OC][64];

    const int oh = blockIdx.x;
    const int n  = blockIdx.y >> 1;
    const int ow0 = (blockIdx.y & 1) * 64;
    const int h  = 2 * oh;
    const int tid = threadIdx.x;

    for (int i = tid; i < OC * 64; i += 256) {
        int ch = i >> 6, owl = i & 63;
        float v = sigma_s[((size_t)(n * OC + ch) * OH + oh) * OW + ow0 + owl];
        p_lds[ch][owl] = v * stats[36 + ch] + stats[54 + ch];
    }
    __syncthreads();

    if (tid < 64) {
        int owl = tid;
        float mx = -1e30f;
#pragma unroll
        for (int ch = 0; ch < OC; ch++) mx = fmaxf(mx, p_lds[ch][owl]);
        float e[OC], sum = 0.f;
#pragma unroll
        for (int ch = 0; ch < OC; ch++) { e[ch] = __expf(p_lds[ch][owl] - mx); sum += e[ch]; }
        float inv = 1.f / sum;
#pragma unroll
        for (int ch = 0; ch < OC; ch++) p_lds[ch][owl] = e[ch] * inv;
    }
    __syncthreads();

    int ihs[3];
#pragma unroll
    for (int kh = 0; kh < 3; kh++) ihs[kh] = refl(h - 1 + kh, H);

#pragma unroll
    for (int it = 0; it < 2; it++) {
        const int flat = it * 256 + tid;
        const int c8 = flat & 7;
        const int owl = flat >> 3;
        const int ow = ow0 + owl;
        const int g = (c8 >= 4) ? 1 : 0;

        float a[8];
#pragma unroll
        for (int j = 0; j < 8; j++) a[j] = 0.f;

#pragma unroll
        for (int kh = 0; kh < 3; kh++) {
            const size_t rb = ((size_t)(n * H + ihs[kh])) * W * 8;
#pragma unroll
            for (int kw = 0; kw < 3; kw++) {
                const int iw = refl(2 * ow - 1 + kw, W);
                const float p = p_lds[g * 9 + kh * 3 + kw][owl];
                uint4 v = xt[rb + (size_t)iw * 8 + c8];
                const unsigned uu[4] = {v.x, v.y, v.z, v.w};
#pragma unroll
                for (int q = 0; q < 4; q++) {
                    float lo = __builtin_bit_cast(float, uu[q] << 16);
                    float hi = __builtin_bit_cast(float, uu[q] & 0xffff0000u);
                    a[2 * q]     = fmaf(p, lo, a[2 * q]);
                    a[2 * q + 1] = fmaf(p, hi, a[2 * q + 1]);
                }
            }
        }

        const size_t ob = ((size_t)(n * CIN + c8 * 8) * OH + oh) * OW + ow;
#pragma unroll
        for (int j = 0; j < 8; j++)
            out[ob + (size_t)j * OH * OW] = a[j];
    }
}

// ---------------------------------------------------------------------------
extern "C" void kernel_launch(void* const* d_in, const int* in_sizes, int n_in,
                              void* d_out, int out_size, void* d_ws, size_t ws_size,
                              hipStream_t stream) {
    const float* x     = (const float*)d_in[0];
    const float* cw    = (const float*)d_in[1];
    const float* gamma = (const float*)d_in[2];
    const float* beta  = (const float*)d_in[3];
    float* out = (float*)d_out;
    float* ws  = (float*)d_ws;

    float* stats   = ws;                                    // 256 floats
    float* sigma_s = ws + 256;                              // 1,179,648 floats
    uint4* wBp     = (uint4*)(sigma_s + (size_t)NB * OC * OH * OW);   // 2304 uint4
    uint4* xtp     = wBp + 36 * 64;                         // 2,097,152 uint4
    float* part    = (float*)(xtp + (size_t)NB * H * W * 8);          // 36*512 floats

    dim3 gT(H, NB + 1);   // y==NB does the weight repack
    nhwc_kernel<<<gT, 256, 0, stream>>>(x, xtp, cw, wBp);

    conv_kernel<<<dim3(NWB), 256, 0, stream>>>(xtp, wBp, sigma_s, part);

    bn_kernel<<<OC, 256, 0, stream>>>(gamma, beta, part, stats);

    dim3 gC(OH, NB * 2);
    out_kernel<<<gC, 256, 0, stream>>>(xtp, sigma_s, stats, out);
}